// Round 10
// baseline (2408.421 us; speedup 1.0000x reference)
//
#include <hip/hip_runtime.h>
#include <hip/hip_bf16.h>

#define HIDDEN   1024
#define XDIM     130
#define CONDDIM  44
#define INDIM    174      // XDIM + CONDDIM
#define NSTEP    16
#define BP       4096     // effective batch (64*64)
#define K0P      1088     // 1024 (h0) + 44 (y) + 20 pad  -> 17 K-tiles of 64
#define K1P      2048     // 1024 (h0') + 1024 (h1)       -> 32 K-tiles of 64
#define GN       4096     // 4*HIDDEN gate dim
#define LGN      256      // padded logits cols (130 -> 256)

typedef __bf16 bf16x8 __attribute__((ext_vector_type(8)));
typedef float  f32x4  __attribute__((ext_vector_type(4)));

// fused gate column order: n in [0,4096) -> q=(n>>4)&3 (gate), j=((n>>6)<<4)|(n&15)
__device__ __forceinline__ int fused_row(int n) {
  const int q = (n >> 4) & 3;
  const int j = ((n >> 6) << 4) | (n & 15);
  return q * HIDDEN + j;
}

// ---------------------------------------------------------------- helpers
__device__ __forceinline__ void g2lds16(const void* g, void* l) {
  __builtin_amdgcn_global_load_lds(
      (const __attribute__((address_space(1))) void*)g,
      (__attribute__((address_space(3))) void*)l, 16, 0, 0);
}

__device__ __forceinline__ float sigm(float x)  { return 1.f / (1.f + __expf(-x)); }
__device__ __forceinline__ float tanhfast(float x) { return 2.f / (1.f + __expf(-2.f * x)) - 1.f; }

// ---------------------------------------------------------------- 256^2 m201-template GEMM + LSTM cell
// gates(4096 x 4096) = A(4096 x K) @ W(4096 x K)^T, fused-gate column order.
// 8 waves (2M x 4N, per-wave 128x64), BK=64.
// LDS: 2 slots x {A-alpha,A-beta,B-alpha,B-beta}[128][64] bf16 = 128 KB.
//   A halves by phase-mh (wave-local row half); B halves by phase-nh (col half).
// Per K-tile: 4 phases (mh,nh) = (0,0),(0,1),(1,0),(1,1):
//   {ds_read (12 or 4; A held across nh) + stage 1 half-tile (2 gloads) ->
//    [lgkmcnt(8) if 12 reads] -> bar -> lgkmcnt(0) -> setprio(1)+16 MFMA+setprio(0) -> bar}
// Stage schedule: ph0:(T+1).B0  ph1:(T+1).B1  ph2:(T+2).A0  ph3:(T+2).A1.
// vmcnt(4) ONCE per K-tile at ph3 (3-5 half-tiles in flight; FIFO covers A).
// Swizzle: 16B chunk c' = c ^ (row&7); LDS dest linear, global SOURCE pre-XORed,
// ds_read applies the same XOR (involution) -> 2-way (free) per quarter-wave beat.
template<bool FB>
__global__ __launch_bounds__(512, 2)
void gemm256_cell_k(const __hip_bfloat16* __restrict__ A,
                    const __hip_bfloat16* __restrict__ W, int K,
                    const float* __restrict__ bcomb,     // 4096, fused order
                    const float* __restrict__ W0T,       // 130 x 4096 fused order (FB only)
                    const int*   __restrict__ idx,       // per-row feedback index (FB only)
                    float* __restrict__ c,
                    __hip_bfloat16* __restrict__ h1dst, int ld1,
                    __hip_bfloat16* __restrict__ h2dst, int ld2)
{
  __shared__ __align__(16) __hip_bfloat16 lds[65536];   // 128 KB

  const int tid  = threadIdx.x;
  const int w    = tid >> 6;        // wave 0..7
  const int lane = tid & 63;
  const int bid  = blockIdx.x;      // 256 blocks
  const int swz  = ((bid & 7) << 5) | (bid >> 3);   // XCD-chunked (256 % 8 == 0)
  const int m0   = (swz >> 4) * 256;
  const int n0   = (swz & 15) * 256;
  const int wm   = w >> 2;          // 0..1 : row half (128 rows)
  const int wn   = w & 3;           // 0..3 : col quarter (64 cols)
  const int fr   = lane & 15;
  const int ks   = lane >> 4;       // k-slot 0..3
  // swizzled 16B-chunk offsets (elements) for kh = 0,1:  c' = (kh*4+ks) ^ (fr&7)
  const int cx0  = ((ks     ^ (fr & 7)) * 8);
  const int cx1  = (((4+ks) ^ (fr & 7)) * 8);
  // staging: lane -> LDS row (lane>>3), chunk (lane&7); source chunk = (lane&7)^(lane>>3)
  const int scx  = (((lane & 7) ^ (lane >> 3)) * 8);
  const int lrow = lane >> 3;       // 0..7
  const int NT   = K >> 6;          // K-tiles of 64

  f32x4 acc[8][4] = {};

  // A stage-half mh: LDS rows L = i*64 + w*8 + lrow; global row = m0 + i*128 + mh*64 + w*8 + lrow
  #define STAGE_AH(T, mh) do {                                                        \
    const int d_ = ((T) & 1);                                                         \
    _Pragma("unroll") for (int i_ = 0; i_ < 2; ++i_)                                  \
      g2lds16(A + (size_t)(m0 + i_ * 128 + (mh) * 64 + w * 8 + lrow) * K              \
                + ((T) * 64 + scx),                                                   \
              (void*)(lds + d_ * 32768 + (mh) * 8192 + (i_ * 64 + w * 8) * 64));      \
  } while (0)
  // B stage-half nh: global col = n0 + (i*2 + (w>>2))*64 + nh*32 + (w&3)*8 + lrow
  #define STAGE_BH(T, nh) do {                                                        \
    const int d_ = ((T) & 1);                                                         \
    _Pragma("unroll") for (int i_ = 0; i_ < 2; ++i_)                                  \
      g2lds16(W + (size_t)(n0 + (i_ * 2 + (w >> 2)) * 64 + (nh) * 32                  \
                           + (w & 3) * 8 + lrow) * K + ((T) * 64 + scx),              \
              (void*)(lds + d_ * 32768 + 16384 + (nh) * 8192 + (i_ * 64 + w * 8) * 64)); \
  } while (0)

  #define READ_A(mh) do {                                                             \
    _Pragma("unroll") for (int q_ = 0; q_ < 4; ++q_) {                                \
      afr[q_][0] = *reinterpret_cast<const bf16x8*>(                                  \
          &Sb[(mh) * 8192 + (wm * 64 + q_ * 16 + fr) * 64 + cx0]);                    \
      afr[q_][1] = *reinterpret_cast<const bf16x8*>(                                  \
          &Sb[(mh) * 8192 + (wm * 64 + q_ * 16 + fr) * 64 + cx1]);                    \
    } } while (0)
  #define READ_B(nh) do {                                                             \
    _Pragma("unroll") for (int nl_ = 0; nl_ < 2; ++nl_) {                             \
      bfr[nl_][0] = *reinterpret_cast<const bf16x8*>(                                 \
          &Sb[16384 + (nh) * 8192 + (wn * 32 + nl_ * 16 + fr) * 64 + cx0]);           \
      bfr[nl_][1] = *reinterpret_cast<const bf16x8*>(                                 \
          &Sb[16384 + (nh) * 8192 + (wn * 32 + nl_ * 16 + fr) * 64 + cx1]);           \
    } } while (0)
  #define MFMA_PH(mh, nh) do {                                                        \
    __builtin_amdgcn_s_setprio(1);                                                    \
    _Pragma("unroll") for (int q_ = 0; q_ < 4; ++q_)                                  \
    _Pragma("unroll") for (int nl_ = 0; nl_ < 2; ++nl_)                               \
    _Pragma("unroll") for (int kh_ = 0; kh_ < 2; ++kh_)                               \
      acc[(mh) * 4 + q_][(nh) * 2 + nl_] = __builtin_amdgcn_mfma_f32_16x16x32_bf16(   \
          afr[q_][kh_], bfr[nl_][kh_], acc[(mh) * 4 + q_][(nh) * 2 + nl_], 0, 0, 0);  \
    __builtin_amdgcn_s_setprio(0);                                                    \
  } while (0)

  #define BAR()   __builtin_amdgcn_s_barrier()
  #define LGKM0() asm volatile("s_waitcnt lgkmcnt(0)" ::: "memory")
  #define LGKM8() asm volatile("s_waitcnt lgkmcnt(8)" ::: "memory")

  // prologue: T0 complete (8 loads) + T1 A-halves (4 loads); wait T0 landed
  STAGE_AH(0, 0); STAGE_AH(0, 1); STAGE_BH(0, 0); STAGE_BH(0, 1);
  STAGE_AH(1, 0); STAGE_AH(1, 1);
  asm volatile("s_waitcnt vmcnt(4)" ::: "memory");
  BAR();

  for (int T = 0; T < NT; ++T) {
    const __hip_bfloat16* Sb = lds + (T & 1) * 32768;
    const bool p1 = (T + 1) < NT;
    const bool p2 = (T + 2) < NT;
    bf16x8 afr[4][2], bfr[2][2];

    // ---- phase (0,0): 12 reads + stage (T+1).B0 ----
    READ_A(0); READ_B(0);
    if (p1) STAGE_BH(T + 1, 0);
    LGKM8(); BAR(); LGKM0();
    MFMA_PH(0, 0);
    BAR();

    // ---- phase (0,1): 4 reads (A held) + stage (T+1).B1 ----
    READ_B(1);
    if (p1) STAGE_BH(T + 1, 1);
    BAR(); LGKM0();
    MFMA_PH(0, 1);
    BAR();

    // ---- phase (1,0): 12 reads + stage (T+2).A0 (A0 dead since ph0) ----
    READ_A(1); READ_B(0);
    if (p2) STAGE_AH(T + 2, 0);
    LGKM8(); BAR(); LGKM0();
    MFMA_PH(1, 0);
    BAR();

    // ---- phase (1,1): 4 reads + stage (T+2).A1 (A1 read issued ph2) ----
    READ_B(1);
    if (p2) STAGE_AH(T + 2, 1);
    BAR(); LGKM0();
    MFMA_PH(1, 1);
    if (p1) {   // once-per-K-tile counted wait: (T+1).B lands, (T+2).A stays in flight
      if (p2) asm volatile("s_waitcnt vmcnt(4)" ::: "memory");
      else    asm volatile("s_waitcnt vmcnt(0)" ::: "memory");
      BAR();
    }
  }
  #undef STAGE_AH
  #undef STAGE_BH
  #undef READ_A
  #undef READ_B
  #undef MFMA_PH
  #undef BAR
  #undef LGKM0
  #undef LGKM8

  // ---- fused LSTM cell epilogue ----
  const int fq = lane >> 4;
  const int cb = n0 + wn * 64;            // quadrant col base (multiple of 64)
  const int j  = ((cb >> 6) << 4) | fr;   // this lane's hidden index

  const float bs0 = bcomb[cb + fr];
  const float bs1 = bcomb[cb + 16 + fr];
  const float bs2 = bcomb[cb + 32 + fr];
  const float bs3 = bcomb[cb + 48 + fr];

  #pragma unroll
  for (int mf = 0; mf < 8; ++mf) {
    #pragma unroll
    for (int r = 0; r < 4; ++r) {
      const int b = m0 + wm * 128 + mf * 16 + fq * 4 + r;
      float gi = acc[mf][0][r] + bs0;
      float gf = acc[mf][1][r] + bs1;
      float gg = acc[mf][2][r] + bs2;
      float go = acc[mf][3][r] + bs3;
      if (FB) {
        const float* wr = W0T + (size_t)idx[b] * GN;
        gi += wr[cb + fr];
        gf += wr[cb + 16 + fr];
        gg += wr[cb + 32 + fr];
        go += wr[cb + 48 + fr];
      }
      const size_t ci = (size_t)b * HIDDEN + j;
      const float cn = sigm(gf) * c[ci] + sigm(gi) * tanhfast(gg);
      c[ci] = cn;
      const float hn = sigm(go) * tanhfast(cn);
      const __hip_bfloat16 hb = __float2bfloat16(hn);
      h1dst[(size_t)b * ld1 + j] = hb;
      if (h2dst) h2dst[(size_t)b * ld2 + j] = hb;
    }
  }
}

// ---------------------------------------------------------------- logits GEMM (64x128 tile, 128 blocks)
__global__ __launch_bounds__(256, 4)
void gemm_bt64_k(const __hip_bfloat16* __restrict__ A, int lda,
                 const __hip_bfloat16* __restrict__ W, int ldw,
                 float* __restrict__ C, int ldc, int K)
{
  __shared__ __align__(16) __hip_bfloat16 As[64 * 32];    // 4 KB
  __shared__ __align__(16) __hip_bfloat16 Bs[128 * 32];   // 8 KB

  const int tid  = threadIdx.x;
  const int w    = tid >> 6;        // wave 0..3
  const int lane = tid & 63;
  const int m0 = blockIdx.y * 64;
  const int n0 = blockIdx.x * 128;
  const int wm = w >> 1;            // 0..1 : 32-row half
  const int wn = w & 1;             // 0..1 : 64-col half
  const int fr = lane & 15;
  const int kqs = (((lane >> 4) ^ ((fr >> 1) & 3)) * 8);   // swizzled read slot
  const int sr  = lane >> 2;
  const int sc  = (((lane & 3) ^ ((sr >> 1) & 3)) * 8);    // pre-swizzled source

  f32x4 acc[2][4] = {};

  for (int k0 = 0; k0 < K; k0 += 32) {
    __syncthreads();
    g2lds16(A + (size_t)(m0 + w * 16 + sr) * lda + (k0 + sc), (void*)(As + (w * 16) * 32));
    g2lds16(W + (size_t)(n0 + w * 16 + sr) * ldw + (k0 + sc), (void*)(Bs + (w * 16) * 32));
    g2lds16(W + (size_t)(n0 + 64 + w * 16 + sr) * ldw + (k0 + sc), (void*)(Bs + (64 + w * 16) * 32));
    __syncthreads();

    bf16x8 af[2], bw[4];
    #pragma unroll
    for (int i = 0; i < 2; ++i)
      af[i] = *reinterpret_cast<const bf16x8*>(&As[(wm * 32 + i * 16 + fr) * 32 + kqs]);
    #pragma unroll
    for (int j = 0; j < 4; ++j)
      bw[j] = *reinterpret_cast<const bf16x8*>(&Bs[(wn * 64 + j * 16 + fr) * 32 + kqs]);
    #pragma unroll
    for (int i = 0; i < 2; ++i)
      #pragma unroll
      for (int j = 0; j < 4; ++j)
        acc[i][j] = __builtin_amdgcn_mfma_f32_16x16x32_bf16(af[i], bw[j], acc[i][j], 0, 0, 0);
  }

  const int fq = lane >> 4;
  #pragma unroll
  for (int i = 0; i < 2; ++i)
    #pragma unroll
    for (int j = 0; j < 4; ++j)
      #pragma unroll
      for (int r = 0; r < 4; ++r) {
        const int row = m0 + wm * 32 + i * 16 + fq * 4 + r;
        const int col = n0 + wn * 64 + j * 16 + fr;
        C[(size_t)row * ldc + col] = acc[i][j][r];
      }
}

// ---------------------------------------------------------------- log_softmax + argmax + y staging
__global__ void smax_k(const float* __restrict__ LG,   // 4096 x LGN logits (no bias yet)
                       const float* __restrict__ bfv,  // bf (130)
                       float* __restrict__ out, int t,
                       const float* __restrict__ x,
                       __hip_bfloat16* __restrict__ A0next,
                       int* __restrict__ idx)
{
  const int b    = blockIdx.x;
  const int lane = threadIdx.x;   // 64
  const float NINF = -__builtin_inff();
  const float* lg = LG + (size_t)b * LGN;

  const int c1 = lane + 64, c2 = lane + 128;
  float v0 = lg[lane] + bfv[lane];
  float v1 = lg[c1] + bfv[c1];
  float v2 = (c2 < XDIM) ? lg[c2] + bfv[c2] : NINF;

  float m = fmaxf(v0, fmaxf(v1, v2));
  #pragma unroll
  for (int o = 32; o > 0; o >>= 1) m = fmaxf(m, __shfl_xor(m, o, 64));

  int bi = 0x7fffffff;
  if (v0 == m) bi = lane;
  if (v1 == m) bi = min(bi, c1);
  if (v2 == m) bi = min(bi, c2);
  #pragma unroll
  for (int o = 32; o > 0; o >>= 1) bi = min(bi, __shfl_xor(bi, o, 64));

  float s = __expf(v0 - m) + __expf(v1 - m) + ((c2 < XDIM) ? __expf(v2 - m) : 0.f);
  #pragma unroll
  for (int o = 32; o > 0; o >>= 1) s += __shfl_xor(s, o, 64);
  const float lse = __logf(s);

  float* orow = out + ((size_t)b * NSTEP + t) * XDIM;
  orow[lane] = v0 - m - lse;
  orow[c1]   = v1 - m - lse;
  if (c2 < XDIM) orow[c2] = v2 - m - lse;
  if (lane == 0) idx[b] = bi;

  if (t + 1 < NSTEP) {   // stage next step's y (+ zero pad) into A0next cols 1024..1087
    const float yv = (lane < CONDDIM)
        ? x[((size_t)b * NSTEP + (t + 1)) * INDIM + XDIM + lane] : 0.f;
    A0next[(size_t)b * K0P + HIDDEN + lane] = __float2bfloat16(yv);
  }
}

// ---------------------------------------------------------------- init + weight packing
__global__ void init_k(const float* __restrict__ z, const float* __restrict__ x,
                       float* __restrict__ c0, float* __restrict__ c1,
                       __hip_bfloat16* __restrict__ A0, __hip_bfloat16* __restrict__ A1,
                       int* __restrict__ idx)
{
  const int t = blockIdx.x * blockDim.x + threadIdx.x;
  if (t >= BP * K1P) return;
  const int b = t >> 11;
  const int j = t & 2047;
  if (j >= HIDDEN)   // A1 second half: h1(-1) = z
    A1[(size_t)b * K1P + j] = __float2bfloat16(z[(size_t)b * HIDDEN + (j - HIDDEN)]);
  if (j < HIDDEN) {
    c0[(size_t)b * HIDDEN + j] = 0.f;
    c1[(size_t)b * HIDDEN + j] = 0.f;
    A0[(size_t)b * K0P + j] = __float2bfloat16(z[(size_t)b * HIDDEN + j]);  // h0(-1) = z
  } else if (j < HIDDEN + 64) {                     // y_0 + zero pad
    const int k = j - HIDDEN;
    const float yv = (k < CONDDIM) ? x[((size_t)b * NSTEP) * INDIM + XDIM + k] : 0.f;
    A0[(size_t)b * K0P + j] = __float2bfloat16(yv);
  }
  if (j == 0) idx[b] = 1;   // o0 one-hot at index 1
}

__global__ void pack0_k(const float* __restrict__ Wih0, const float* __restrict__ Whh0,
                        const float* __restrict__ bih0, const float* __restrict__ bhh0,
                        __hip_bfloat16* __restrict__ Wc0, float* __restrict__ bc0)
{
  const int t = blockIdx.x * blockDim.x + threadIdx.x;
  if (t >= GN * K0P) return;
  const int n = t / K0P, k = t % K0P;
  const int row = fused_row(n);
  float v = 0.f;
  if (k < HIDDEN)                v = Whh0[(size_t)row * HIDDEN + k];
  else if (k < HIDDEN + CONDDIM) v = Wih0[(size_t)row * INDIM + XDIM + (k - HIDDEN)];
  Wc0[t] = __float2bfloat16(v);
  if (k == 0) bc0[n] = bih0[row] + bhh0[row];
}

__global__ void pack1_k(const float* __restrict__ Wih1, const float* __restrict__ Whh1,
                        const float* __restrict__ bih1, const float* __restrict__ bhh1,
                        __hip_bfloat16* __restrict__ Wc1, float* __restrict__ bc1)
{
  const int t = blockIdx.x * blockDim.x + threadIdx.x;
  if (t >= GN * K1P) return;
  const int n = t >> 11, k = t & 2047;
  const int row = fused_row(n);
  const float v = (k < HIDDEN) ? Wih1[(size_t)row * HIDDEN + k]
                               : Whh1[(size_t)row * HIDDEN + (k - HIDDEN)];
  Wc1[t] = __float2bfloat16(v);
  if (k == 0) bc1[n] = bih1[row] + bhh1[row];
}

__global__ void packf_k(const float* __restrict__ Wf, __hip_bfloat16* __restrict__ Wfp)
{
  const int t = blockIdx.x * blockDim.x + threadIdx.x;
  if (t >= LGN * HIDDEN) return;
  const int r = t >> 10, k = t & 1023;
  const float v = (r < XDIM) ? Wf[(size_t)r * HIDDEN + k] : 0.f;
  Wfp[t] = __float2bfloat16(v);
}

__global__ void packt_k(const float* __restrict__ Wih0, float* __restrict__ W0T)
{
  const int t = blockIdx.x * blockDim.x + threadIdx.x;
  if (t >= XDIM * GN) return;
  const int e = t >> 12, n = t & 4095;      // W0T[e][n] = Wih0[fused_row(n)][e]
  W0T[t] = Wih0[(size_t)fused_row(n) * INDIM + e];
}

// ---------------------------------------------------------------- launch
extern "C" void kernel_launch(void* const* d_in, const int* in_sizes, int n_in,
                              void* d_out, int out_size, void* d_ws, size_t ws_size,
                              hipStream_t stream)
{
  const float* z    = (const float*)d_in[0];
  const float* x    = (const float*)d_in[1];
  const float* Wih0 = (const float*)d_in[2];
  const float* Whh0 = (const float*)d_in[3];
  const float* bih0 = (const float*)d_in[4];
  const float* bhh0 = (const float*)d_in[5];
  const float* Wih1 = (const float*)d_in[6];
  const float* Whh1 = (const float*)d_in[7];
  const float* bih1 = (const float*)d_in[8];
  const float* bhh1 = (const float*)d_in[9];
  const float* Wf   = (const float*)d_in[10];
  const float* bfv  = (const float*)d_in[11];
  float* out = (float*)d_out;

  char* ws = (char*)d_ws;
  size_t off = 0;
  auto alloc = [&](size_t bytes) { void* p = ws + off; off += (bytes + 255) & ~(size_t)255; return p; };

  float*          LG  = (float*)         alloc((size_t)BP * LGN * 4);      // logits
  __hip_bfloat16* A0a = (__hip_bfloat16*)alloc((size_t)BP * K0P * 2);
  __hip_bfloat16* A0b = (__hip_bfloat16*)alloc((size_t)BP * K0P * 2);
  __hip_bfloat16* A1a = (__hip_bfloat16*)alloc((size_t)BP * K1P * 2);
  __hip_bfloat16* A1b = (__hip_bfloat16*)alloc((size_t)BP * K1P * 2);
  __hip_bfloat16* Wc0 = (__hip_bfloat16*)alloc((size_t)GN * K0P * 2);
  __hip_bfloat16* Wc1 = (__hip_bfloat16*)alloc((size_t)GN * K1P * 2);
  __hip_bfloat16* Wfp = (__hip_bfloat16*)alloc((size_t)LGN * HIDDEN * 2);
  float*          W0T = (float*)         alloc((size_t)XDIM * GN * 4);
  float*          bc0 = (float*)         alloc((size_t)GN * 4);
  float*          bc1 = (float*)         alloc((size_t)GN * 4);
  float*          c0  = (float*)         alloc((size_t)BP * HIDDEN * 4);
  float*          c1  = (float*)         alloc((size_t)BP * HIDDEN * 4);
  int*            idx = (int*)           alloc((size_t)BP * 4);
  (void)ws_size; (void)in_sizes; (void)n_in; (void)out_size;

  pack0_k<<<(GN * K0P + 255) / 256, 256, 0, stream>>>(Wih0, Whh0, bih0, bhh0, Wc0, bc0);
  pack1_k<<<(GN * K1P + 255) / 256, 256, 0, stream>>>(Wih1, Whh1, bih1, bhh1, Wc1, bc1);
  packf_k<<<(LGN * HIDDEN + 255) / 256, 256, 0, stream>>>(Wf, Wfp);
  packt_k<<<(XDIM * GN + 255) / 256, 256, 0, stream>>>(Wih0, W0T);
  init_k<<<(BP * K1P + 255) / 256, 256, 0, stream>>>(z, x, c0, c1, A0a, A1a, idx);

  for (int t = 0; t < NSTEP; ++t) {
    __hip_bfloat16* A0c = (t & 1) ? A0b : A0a;
    __hip_bfloat16* A0n = (t & 1) ? A0a : A0b;
    __hip_bfloat16* A1c = (t & 1) ? A1b : A1a;
    __hip_bfloat16* A1n = (t & 1) ? A1a : A1b;

    // layer 0: gates = [h0|y] @ [Whh0|Wih0_y]^T, fused cell -> h0'
    gemm256_cell_k<true><<<256, 512, 0, stream>>>(
        A0c, Wc0, K0P, bc0, W0T, idx, c0,
        A1c, K1P,        // h0' -> A1 (current) first half, read by GEMM1 this step
        A0n, K0P);       // h0' -> A0 (next step)
    // layer 1: gates = [h0'|h1] @ [Wih1|Whh1]^T, fused cell -> h1'
    gemm256_cell_k<false><<<256, 512, 0, stream>>>(
        A1c, Wc1, K1P, bc1, nullptr, nullptr, c1,
        A1n + HIDDEN, K1P,   // h1' -> A1 (next) second half
        nullptr, 0);
    // logits = h1' @ Wf^T  (64x128 tile, 128 blocks)
    gemm_bt64_k<<<dim3(LGN / 128, BP / 64), dim3(256), 0, stream>>>(
        A1n + HIDDEN, K1P, Wfp, HIDDEN, LG, LGN, HIDDEN);
    smax_k<<<BP, 64, 0, stream>>>(LG, bfv, out, t, x, A0n, idx);
  }
}